// Round 5
// baseline (122.397 us; speedup 1.0000x reference)
//
#include <hip/hip_runtime.h>

// Guitar string (Karplus-Strong waveguide), MI355X gfx950.
//
// LTI reformulation (validated rounds 2-6): A (l->r, 2 taps) and B (r->l,
// 4 taps) commute; both parities evolve by C = A*B (5 taps, lag QB=DU+DD+2).
// Evolve y_m = (C^8)^m (0.5 e) (33 taps, lag 8QB); E14 = sum_{0..14} y_m;
//   E61 = (1+C^2)(1+C^4) E14 + (1+C^2) y15,  z62 = C^4 y15,
//   U = (1+C) E61 + z62,  ls = (1+B)U + C z62,  rs = (1+A)U + C z62.
//
// Round 12: back to the exact r0 structure (71.8us; r8-r11 all regressed:
// reg-budget pin, tap-dekernelization, C^16 all falsified -- C^16 spilled,
// WRITE_SIZE 37.5MB). r0's residual: ~50% of time is per-step stall
// (lgkmcnt drain + s_barrier + 12x ds_read refill) with all 16 waves
// LOCKSTEP, so no co-resident work hides it. But the true dependency is
// only 2 waves deep (window reach E8+48 <= 1096 < 2048). This round
// replaces the 15 evolve __syncthreads with a per-wave LDS flag chain:
//   prog[w]: steps whose stores are drained; rdp[w]: steps whose window
//   loads are done. Step s: spin prog[w-1,w-2]>=s -> loads -> lgkmcnt(0)
//   -> rdp[w]=s+1 -> compute -> spin rdp[w+1,w+2]>=s (WAR: our write
//   region is read by w+1,w+2 one parity back) -> stores -> lgkmcnt(0)
//   -> prog[w]=s+1. Dead waves bump flags (garbage regions below the
//   validity boundary were already read-tolerated in r0). DAG is acyclic.
//   Waves de-synchronize -> one wave's drain/refill overlaps others' FMAs.
// Epilogue/combine keep r0 barriers (convert next round if this works).
// Kept from r8 (twice-validated): pass-1 sg fetch trim to s4 >= F0-600.
//
// Geometry: 64 rows x 4 chunks of 8000. SPAN=16384, HALO=8384 >= 8*E8
// (E8=8QB in {1040,1048}). Pass1: F0=7*E8<=7336; epilogue worst-case
// reach 63*QB+DD+13 = 8382 <= 8384. PADF=1056 >= E8.

#define TLEN   32000
#define NROW   64
#define CHUNK  8000
#define NTH    1024
#define NWV    (NTH/64)
#define PT     16
#define PT4    (PT/4)
#define SPAN   (NTH*PT)        // 16384
#define HALO   (SPAN-CHUNK)    // 8384
#define PADF   1056            // front zero pad >= E8 max (1048)
#define BUF    (PADF+SPAN)     // 17440 floats = 69.76 KB per buffer

__device__ inline int swz4(int f) {        // f: float index, multiple of 4
  int B = f >> 2;
  B ^= (B >> 3) & 7;                       // permute 16B blocks in 8-groups
  return B << 2;
}

__device__ inline float sgprf(float x) {
  return __uint_as_float(__builtin_amdgcn_readfirstlane(__float_as_uint(x)));
}

// Spin until LDS flag >= v. Broadcast read (conflict-free); sleep while
// waiting; memory clobber + sched_barrier stop the compiler from hoisting
// subsequent LDS data reads above the spin (rule #18 analog).
__device__ inline void spinge(const int* f, int v) {
  while (((const volatile int*)f)[0] < v) __builtin_amdgcn_s_sleep(1);
  asm volatile("" ::: "memory");
  __builtin_amdgcn_sched_barrier(0);
}

struct Cf { int DU, DD, QB; float a[2], b[4], q[5], q2[9], q4[17], q8[33]; };

__device__ inline void build_from(float Lf, float pv, Cf& c) {
  const float p   = 0.1f + 0.8f * pv;
  const float nUp = Lf * p;
  const float nDn = Lf * (1.0f - p);
  c.DU = (int)ceilf(nUp);
  c.DD = (int)ceilf(nDn);
  const float fU = (float)c.DU - nUp;
  const float fD = (float)c.DD - nDn;
  const float GN  = -0.99f * 0.999f;        // NUT * VIB
  const float GB2 = -0.99f * 0.999f * 0.5f; // BRIDGE * VIB * 0.5
  c.a[0] = GN * (1.0f - fU);                // A: lag DU - i
  c.a[1] = GN * fU;
  const float w0 = 1.0f - fD, w1 = fD;
  c.b[0] = GB2 * (0.3f * w0);               // B: lag DD+2 - i
  c.b[1] = GB2 * (w0 + 0.3f * w1);
  c.b[2] = GB2 * (0.7f * w0 + w1);
  c.b[3] = GB2 * (0.7f * w1);
  c.QB = c.DU + c.DD + 2;                   // C: lag QB - i
#pragma unroll
  for (int m = 0; m < 5; ++m) c.q[m] = 0.f;
#pragma unroll
  for (int i = 0; i < 2; ++i)
#pragma unroll
    for (int j = 0; j < 4; ++j) c.q[i+j] = fmaf(c.a[i], c.b[j], c.q[i+j]);
#pragma unroll
  for (int m = 0; m < 9; ++m) c.q2[m] = 0.f;
#pragma unroll
  for (int i = 0; i < 5; ++i)
#pragma unroll
    for (int j = 0; j < 5; ++j) c.q2[i+j] = fmaf(c.q[i], c.q[j], c.q2[i+j]);
#pragma unroll
  for (int m = 0; m < 17; ++m) c.q4[m] = 0.f;
#pragma unroll
  for (int i = 0; i < 9; ++i)
#pragma unroll
    for (int j = 0; j < 9; ++j) c.q4[i+j] = fmaf(c.q2[i], c.q2[j], c.q4[i+j]);
#pragma unroll
  for (int m = 0; m < 33; ++m) c.q8[m] = 0.f;
#pragma unroll
  for (int i = 0; i < 17; ++i)
#pragma unroll
    for (int j = 0; j < 17; ++j) c.q8[i+j] = fmaf(c.q4[i], c.q4[j], c.q8[i+j]);
}

template<int NF4>
__device__ inline void ldwin(const float* b, int basef, float* v) {
#pragma unroll
  for (int i = 0; i < NF4; ++i) {
    float4 t4 = *(const float4*)&b[swz4(basef + 4*i)];
    v[4*i+0] = t4.x; v[4*i+1] = t4.y; v[4*i+2] = t4.z; v[4*i+3] = t4.w;
  }
}

__device__ inline void stown(float* b, const int* wro, const float* v) {
#pragma unroll
  for (int k = 0; k < PT4; ++k)
    *(float4*)&b[wro[k]] = make_float4(v[4*k], v[4*k+1], v[4*k+2], v[4*k+3]);
}

__global__ __launch_bounds__(NTH, 4)
void gs_pass(const int* __restrict__ lenp, const float* __restrict__ pp,
             const float* __restrict__ exc,
             float* __restrict__ zg, float* __restrict__ sg,
             float* __restrict__ lout, float* __restrict__ rout, int pass)
{
  __shared__ __align__(16) float bufA[BUF];
  __shared__ __align__(16) float bufB[BUF];
  __shared__ int progF[NWV];   // per-wave: steps with stores drained
  __shared__ int rdpF[NWV];    // per-wave: steps with window loads done

  const int row   = blockIdx.x >> 2;
  const int chunk = blockIdx.x & 3;
  const int t0    = chunk * CHUNK;
  const int tid   = threadIdx.x;
  const int sbase = tid * PT;
  const size_t rb = (size_t)row * TLEN;
  const int steps = pass ? 7 : 8;
  const int w     = tid >> 6;
  const int wtop  = ((w + 1) << 6) * PT;   // wave's max sbase+PT

  if (tid < NWV) { progF[tid] = 0; rdpF[tid] = 0; }

  // ---- taps for the evolve loop (W in SGPRs; only E8 else stays live) ----
  int E8;
  float W[33];
  {
    Cf c0; build_from((float)lenp[0], pp[0], c0);
#pragma unroll
    for (int m = 0; m < 33; ++m) W[m] = sgprf(c0.q8[m]);
    E8 = 8 * c0.QB;                       // multiple of 8, in {1040,1048}
  }

  // ---- precomputed swizzled offsets ----
  int rdo[12], wro[PT4];
#pragma unroll
  for (int i = 0; i < 12; ++i) rdo[i] = swz4(PADF + sbase - E8 + 4*i);
#pragma unroll
  for (int k = 0; k < PT4; ++k) wro[k] = swz4(PADF + sbase + 4*k);

  // ---- staging ----
  const float4 f4z = make_float4(0.f, 0.f, 0.f, 0.f);
  if (tid * 4 < PADF) {                                // zero front pads
    *(float4*)&bufA[swz4(tid*4)] = f4z;
    *(float4*)&bufB[swz4(tid*4)] = f4z;
  }
  if (chunk == 0) {                                    // true zeros at t<0
    for (int s4 = tid*4; s4 < HALO; s4 += NTH*4)
      *(float4*)&bufB[swz4(PADF + s4)] = f4z;
  }
#pragma unroll
  for (int k = 0; k < 4; ++k) {                        // coalesced state load
    int s4 = tid*4 + k*(NTH*4);
    int t  = t0 - HALO + s4;
    float4 v = f4z;
    if (t >= 0) {
      if (pass == 0) {
        float4 e = *(const float4*)&exc[rb + t];
        v = make_float4(0.5f*e.x, 0.5f*e.y, 0.5f*e.z, 0.5f*e.w);
      } else {
        v = *(const float4*)&zg[rb + t];
      }
    }
    *(float4*)&bufA[swz4(PADF + s4)] = v;
  }
  __syncthreads();

  float* cur = bufA;
  float* nxt = bufB;

  // own samples + partial sum
  float z[PT], acc[PT];
#pragma unroll
  for (int k = 0; k < PT4; ++k) {
    float4 t4 = *(const float4*)&cur[wro[k]];
    z[4*k+0] = t4.x; z[4*k+1] = t4.y; z[4*k+2] = t4.z; z[4*k+3] = t4.w;
  }
#pragma unroll
  for (int j = 0; j < PT; ++j) acc[j] = 0.f;

  // ---- evolve: per-wave flag chain instead of block barriers ----
  for (int s = 0; s < steps; ++s) {
    const int limit = (chunk == 0) ? HALO : (s + 1) * E8;
    const bool walive = (wtop > limit);
    const bool alive  = (sbase + PT > limit);
    if (walive) {
      if (s > 0) {                         // RAW: producers' stores drained
        if (w >= 1) spinge(&progF[w-1], s);
        if (w >= 2) spinge(&progF[w-2], s);
      }
      float v[48];                         // PT + 32 floats, 16B-aligned
      if (alive) {
#pragma unroll
        for (int i = 0; i < 12; ++i) {
          float4 t4 = *(const float4*)&cur[rdo[i]];
          v[4*i+0] = t4.x; v[4*i+1] = t4.y; v[4*i+2] = t4.z; v[4*i+3] = t4.w;
        }
      }
      asm volatile("s_waitcnt lgkmcnt(0)" ::: "memory");
      if ((tid & 63) == 0) ((volatile int*)rdpF)[w] = s + 1;
      if (alive) {
#pragma unroll
        for (int j = 0; j < PT; ++j) acc[j] += z[j];
#pragma unroll
        for (int j = 0; j < PT; ++j) {
          float sv = W[0] * v[j];
#pragma unroll
          for (int m = 1; m < 33; ++m) sv = fmaf(W[m], v[j+m], sv);
          z[j] = sv;
        }
      }
      // WAR: waves w+1,w+2 read our region (one parity back) in step s-1
      if (w + 1 < NWV) spinge(&rdpF[w+1], s);
      if (w + 2 < NWV) spinge(&rdpF[w+2], s);
      if (alive) stown(nxt, wro, z);
      asm volatile("s_waitcnt lgkmcnt(0)" ::: "memory");
      if ((tid & 63) == 0) ((volatile int*)progF)[w] = s + 1;
    } else {
      if ((tid & 63) == 0) {
        ((volatile int*)rdpF)[w]  = s + 1;
        ((volatile int*)progF)[w] = s + 1;
      }
    }
    float* tp = cur; cur = nxt; nxt = tp;
  }
  __syncthreads();                         // converge before cross-wave use

  if (pass == 0) {
    // cur = y8, stage acc; writeback own region.
    stown(nxt, wro, acc);
    __syncthreads();
#pragma unroll
    for (int k = 0; k < 2; ++k) {
      int s4 = HALO + tid*4 + k*(NTH*4);
      if (s4 < SPAN) {
        int t = t0 + s4 - HALO;
        *(float4*)&zg[rb + t] = *(const float4*)&cur[swz4(PADF + s4)];
        *(float4*)&sg[rb + t] = *(const float4*)&nxt[swz4(PADF + s4)];
      }
    }
    return;
  }

  // ================= pass 1 epilogue (cur = y15, z = y15 own) ===========
  const int F0 = 7 * E8;
  // P0: E14 = acc + sg (L3-hot from pass 0) into nxt, trimmed to the
  // epilogue's reach (deepest mattering E14 read ~= F0-480).
  stown(nxt, wro, acc);
  __syncthreads();
#pragma unroll
  for (int k = 0; k < 4; ++k) {
    int s4 = tid*4 + k*(NTH*4);
    int t  = t0 - HALO + s4;
    float4 sv = f4z;
    if (t >= 0 && (chunk == 0 || s4 >= F0 - 600))
      sv = *(const float4*)&sg[rb + t];
    int o = swz4(PADF + s4);
    float4 a4 = *(const float4*)&nxt[o];
    *(float4*)&nxt[o] = make_float4(a4.x + sv.x, a4.y + sv.y,
                                    a4.z + sv.z, a4.w + sv.w);
  }
  __syncthreads();

  // Rebuild taps (volatile re-reads keep the evolve loop lean); SGPR-hoist.
  Cf c;
  {
    volatile const int* vl = lenp;
    volatile const float* vp = pp;
    build_from((float)vl[0], vp[0], c);
  }
  const int L2 = 2*c.QB, L4 = 4*c.QB, LQ = c.QB, LB = c.DD + 2, LA = c.DU;
  const int L2e = (L2+3)&~3, sh2 = L2e-L2;
  const int LQe = (LQ+3)&~3, shq = LQe-LQ;
  const int LBe = (LB+3)&~3, shb = LBe-LB;
  const int LAe = (LA+3)&~3, sha = LAe-LA;
  float q4f[17], T2[12], TQ[8], TB[7], TA[5];
#pragma unroll
  for (int i = 0; i < 17; ++i) q4f[i] = sgprf(c.q4[i]);
#pragma unroll
  for (int m = 0; m < 12; ++m) {
    float v = 0.f;
#pragma unroll
    for (int i = 0; i < 9; ++i) if (m == sh2 + i) v = c.q2[i];
    T2[m] = sgprf(v);
  }
#pragma unroll
  for (int m = 0; m < 8; ++m) {
    float v = 0.f;
#pragma unroll
    for (int i = 0; i < 5; ++i) if (m == shq + i) v = c.q[i];
    TQ[m] = sgprf(v);
  }
#pragma unroll
  for (int m = 0; m < 7; ++m) {
    float v = 0.f;
#pragma unroll
    for (int i = 0; i < 4; ++i) if (m == shb + i) v = c.b[i];
    TB[m] = sgprf(v);
  }
#pragma unroll
  for (int m = 0; m < 5; ++m) {
    float v = 0.f;
#pragma unroll
    for (int i = 0; i < 2; ++i) if (m == sha + i) v = c.a[i];
    TA[m] = sgprf(v);
  }

  const bool ae = (chunk == 0) || (sbase + PT > F0);

  // Ph-A: H1 = (1+C^2)E14 ; Y2 = (1+C^2)y15 ; z62 = C^4 y15
  float H1[PT], Y2[PT], z62[PT];
  if (ae) {
    float e0[PT];
#pragma unroll
    for (int k = 0; k < PT4; ++k) {
      float4 t4 = *(const float4*)&nxt[wro[k]];
      e0[4*k+0] = t4.x; e0[4*k+1] = t4.y; e0[4*k+2] = t4.z; e0[4*k+3] = t4.w;
    }
    float wv[28];
    ldwin<7>(nxt, PADF + sbase - L2e, wv);
#pragma unroll
    for (int j = 0; j < PT; ++j) {
      float sv = e0[j];
#pragma unroll
      for (int m = 0; m < 12; ++m) sv = fmaf(T2[m], wv[j+m], sv);
      H1[j] = sv;
    }
    ldwin<7>(cur, PADF + sbase - L2e, wv);
#pragma unroll
    for (int j = 0; j < PT; ++j) {
      float sv = z[j];
#pragma unroll
      for (int m = 0; m < 12; ++m) sv = fmaf(T2[m], wv[j+m], sv);
      Y2[j] = sv;
    }
    float w4[32];
    ldwin<8>(cur, PADF + sbase - L4, w4);    // L4 = 4QB, multiple of 4
#pragma unroll
    for (int j = 0; j < PT; ++j) {
      float sv = q4f[0] * w4[j];
#pragma unroll
      for (int m = 1; m < 17; ++m) sv = fmaf(q4f[m], w4[j+m], sv);
      z62[j] = sv;
    }
  }
  __syncthreads();
  if (ae) { stown(nxt, wro, H1); stown(cur, wro, z62); }
  __syncthreads();

  // Ph-B: E61 = H1 + C^4 H1 + Y2
  float E61[PT];
  if (ae) {
    float w4[32];
    ldwin<8>(nxt, PADF + sbase - L4, w4);
#pragma unroll
    for (int j = 0; j < PT; ++j) {
      float sv = H1[j] + Y2[j];
#pragma unroll
      for (int m = 0; m < 17; ++m) sv = fmaf(q4f[m], w4[j+m], sv);
      E61[j] = sv;
    }
  }
  __syncthreads();
  if (ae) stown(nxt, wro, E61);
  __syncthreads();

  // Ph-C: U = E61 + C E61 + z62 ; V = C z62
  float U[PT], V[PT];
  if (ae) {
    float wv[24];
    ldwin<6>(nxt, PADF + sbase - LQe, wv);
#pragma unroll
    for (int j = 0; j < PT; ++j) {
      float sv = E61[j] + z62[j];
#pragma unroll
      for (int m = 0; m < 8; ++m) sv = fmaf(TQ[m], wv[j+m], sv);
      U[j] = sv;
    }
    ldwin<6>(cur, PADF + sbase - LQe, wv);
#pragma unroll
    for (int j = 0; j < PT; ++j) {
      float sv = TQ[0] * wv[j];
#pragma unroll
      for (int m = 1; m < 8; ++m) sv = fmaf(TQ[m], wv[j+m], sv);
      V[j] = sv;
    }
  }
  __syncthreads();
  if (ae) stown(nxt, wro, U);
  __syncthreads();

  // Ph-D: s0 = U+V (into V); ls = s0 + B U; rs = s0 + A U
  float LSv[PT], RSv[PT];
  if (ae) {
#pragma unroll
    for (int j = 0; j < PT; ++j) V[j] += U[j];
    {
      float wb[24];
      ldwin<6>(nxt, PADF + sbase - LBe, wb);
#pragma unroll
      for (int j = 0; j < PT; ++j) {
        float sv = V[j];
#pragma unroll
        for (int m = 0; m < 7; ++m) sv = fmaf(TB[m], wb[j+m], sv);
        LSv[j] = sv;
      }
    }
    {
      float wa[20];
      ldwin<5>(nxt, PADF + sbase - LAe, wa);
#pragma unroll
      for (int j = 0; j < PT; ++j) {
        float sv = V[j];
#pragma unroll
        for (int m = 0; m < 5; ++m) sv = fmaf(TA[m], wa[j+m], sv);
        RSv[j] = sv;
      }
    }
  }
  __syncthreads();
  if (ae) { stown(cur, wro, LSv); stown(nxt, wro, RSv); }
  __syncthreads();

  // coalesced output store
#pragma unroll
  for (int k = 0; k < 2; ++k) {
    int s4 = HALO + tid*4 + k*(NTH*4);
    if (s4 < SPAN) {
      int t = t0 + s4 - HALO;
      *(float4*)&lout[rb + t] = *(const float4*)&cur[swz4(PADF + s4)];
      *(float4*)&rout[rb + t] = *(const float4*)&nxt[swz4(PADF + s4)];
    }
  }
}

extern "C" void kernel_launch(void* const* d_in, const int* in_sizes, int n_in,
                              void* d_out, int out_size, void* d_ws, size_t ws_size,
                              hipStream_t stream) {
  (void)in_sizes; (void)n_in; (void)out_size; (void)ws_size;

  const int*   lenp = (const int*)d_in[0];
  const float* pp   = (const float*)d_in[1];
  const float* exc  = (const float*)d_in[2];

  float* lout = (float*)d_out;                  // ls: 64*32000 f32
  float* rout = lout + (size_t)NROW * TLEN;     // rs

  float* zg = (float*)d_ws;                     // state y8
  float* sg = zg + (size_t)NROW * TLEN;         // partial sum y0..y7

  dim3 grid(NROW * 4);
  gs_pass<<<grid, dim3(NTH), 0, stream>>>(lenp, pp, exc, zg, sg, lout, rout, 0);
  gs_pass<<<grid, dim3(NTH), 0, stream>>>(lenp, pp, exc, zg, sg, lout, rout, 1);
}

// Round 6
// 89.115 us; speedup vs baseline: 1.3735x; 1.3735x over previous
//
#include <hip/hip_runtime.h>

// Guitar string (Karplus-Strong waveguide), MI355X gfx950.
//
// LTI reformulation (validated rounds 2-6): A (l->r, 2 taps) and B (r->l,
// 4 taps) commute; both parities evolve by C = A*B (5 taps, lag QB=DU+DD+2).
// Evolve y_m = (C^8)^m (0.5 e) (33 taps, lag 8QB); E14 = sum_{0..14} y_m;
//   E61 = (1+C^2)(1+C^4) E14 + (1+C^2) y15,  z62 = C^4 y15,
//   U = (1+C) E61 + z62,  ls = (1+B)U + C z62,  rs = (1+A)U + C z62.
//
// Round 13: r8-r12 all falsified (reg pin, tap offload, C^16, flag chain
// -- each either spilled at the hard 64-VGPR allocation or serialized).
// Rule learned: do not touch the evolve loop's streaming schedule.
// This round removes pure-bookkeeping epochs only, r0 otherwise intact:
//  - pass-0: step-7 store+barrier dropped (no LDS reader of y8); zg/sg
//    written DIRECTLY from registers (own layout, no LDS roundtrip).
//  - pass-1 P0: sg loaded in OWN layout and added to acc in registers
//    (same position predicate as the validated F0-600 trim -> bit-identical
//    E14); one stown; RMW epoch gone.
//  - Ph-A: e0 == acc (registers), 4 ds_reads dropped.
//  - Ph-D: computed only for output threads (sbase >= HALO); ls/rs stored
//    straight to global from registers; final stow/store epochs gone.
//
// Geometry: 64 rows x 4 chunks of 8000. SPAN=16384, HALO=8384 >= 8*E8
// (E8=8QB<=1048; QB<=131 since nUp+nDn=128). Pass1: F0=7*E8<=7336; epilogue
// worst-case reach 63*QB+DD+13 = 8382 <= 8384. PADF=1056 >= E8.

#define TLEN   32000
#define NROW   64
#define CHUNK  8000
#define NTH    1024
#define PT     16
#define PT4    (PT/4)
#define SPAN   (NTH*PT)        // 16384
#define HALO   (SPAN-CHUNK)    // 8384 (multiple of 16)
#define PADF   1056            // front zero pad >= E8 max (1048)
#define BUF    (PADF+SPAN)     // 17440 floats = 69.76 KB per buffer

__device__ inline int swz4(int f) {        // f: float index, multiple of 4
  int B = f >> 2;
  B ^= (B >> 3) & 7;                       // permute 16B blocks in 8-groups
  return B << 2;
}

__device__ inline float sgprf(float x) {
  return __uint_as_float(__builtin_amdgcn_readfirstlane(__float_as_uint(x)));
}

struct Cf { int DU, DD, QB; float a[2], b[4], q[5], q2[9], q4[17], q8[33]; };

__device__ inline void build_from(float Lf, float pv, Cf& c) {
  const float p   = 0.1f + 0.8f * pv;
  const float nUp = Lf * p;
  const float nDn = Lf * (1.0f - p);
  c.DU = (int)ceilf(nUp);
  c.DD = (int)ceilf(nDn);
  const float fU = (float)c.DU - nUp;
  const float fD = (float)c.DD - nDn;
  const float GN  = -0.99f * 0.999f;        // NUT * VIB
  const float GB2 = -0.99f * 0.999f * 0.5f; // BRIDGE * VIB * 0.5
  c.a[0] = GN * (1.0f - fU);                // A: lag DU - i
  c.a[1] = GN * fU;
  const float w0 = 1.0f - fD, w1 = fD;
  c.b[0] = GB2 * (0.3f * w0);               // B: lag DD+2 - i
  c.b[1] = GB2 * (w0 + 0.3f * w1);
  c.b[2] = GB2 * (0.7f * w0 + w1);
  c.b[3] = GB2 * (0.7f * w1);
  c.QB = c.DU + c.DD + 2;                   // C: lag QB - i
#pragma unroll
  for (int m = 0; m < 5; ++m) c.q[m] = 0.f;
#pragma unroll
  for (int i = 0; i < 2; ++i)
#pragma unroll
    for (int j = 0; j < 4; ++j) c.q[i+j] = fmaf(c.a[i], c.b[j], c.q[i+j]);
#pragma unroll
  for (int m = 0; m < 9; ++m) c.q2[m] = 0.f;
#pragma unroll
  for (int i = 0; i < 5; ++i)
#pragma unroll
    for (int j = 0; j < 5; ++j) c.q2[i+j] = fmaf(c.q[i], c.q[j], c.q2[i+j]);
#pragma unroll
  for (int m = 0; m < 17; ++m) c.q4[m] = 0.f;
#pragma unroll
  for (int i = 0; i < 9; ++i)
#pragma unroll
    for (int j = 0; j < 9; ++j) c.q4[i+j] = fmaf(c.q2[i], c.q2[j], c.q4[i+j]);
#pragma unroll
  for (int m = 0; m < 33; ++m) c.q8[m] = 0.f;
#pragma unroll
  for (int i = 0; i < 17; ++i)
#pragma unroll
    for (int j = 0; j < 17; ++j) c.q8[i+j] = fmaf(c.q4[i], c.q4[j], c.q8[i+j]);
}

template<int NF4>
__device__ inline void ldwin(const float* b, int basef, float* v) {
#pragma unroll
  for (int i = 0; i < NF4; ++i) {
    float4 t4 = *(const float4*)&b[swz4(basef + 4*i)];
    v[4*i+0] = t4.x; v[4*i+1] = t4.y; v[4*i+2] = t4.z; v[4*i+3] = t4.w;
  }
}

__device__ inline void stown(float* b, const int* wro, const float* v) {
#pragma unroll
  for (int k = 0; k < PT4; ++k)
    *(float4*)&b[wro[k]] = make_float4(v[4*k], v[4*k+1], v[4*k+2], v[4*k+3]);
}

__global__ __launch_bounds__(NTH, 4)
void gs_pass(const int* __restrict__ lenp, const float* __restrict__ pp,
             const float* __restrict__ exc,
             float* __restrict__ zg, float* __restrict__ sg,
             float* __restrict__ lout, float* __restrict__ rout, int pass)
{
  __shared__ __align__(16) float bufA[BUF];
  __shared__ __align__(16) float bufB[BUF];

  const int row   = blockIdx.x >> 2;
  const int chunk = blockIdx.x & 3;
  const int t0    = chunk * CHUNK;
  const int tid   = threadIdx.x;
  const int sbase = tid * PT;
  const size_t rb = (size_t)row * TLEN;

  // ---- taps for the evolve loop (W in SGPRs; only E8 else stays live) ----
  int E8;
  float W[33];
  {
    Cf c0; build_from((float)lenp[0], pp[0], c0);
#pragma unroll
    for (int m = 0; m < 33; ++m) W[m] = sgprf(c0.q8[m]);
    E8 = 8 * c0.QB;                       // multiple of 8, <= 1048
  }

  // ---- precomputed swizzled offsets ----
  int rdo[12], wro[PT4];
#pragma unroll
  for (int i = 0; i < 12; ++i) rdo[i] = swz4(PADF + sbase - E8 + 4*i);
#pragma unroll
  for (int k = 0; k < PT4; ++k) wro[k] = swz4(PADF + sbase + 4*k);

  // ---- staging ----
  const float4 f4z = make_float4(0.f, 0.f, 0.f, 0.f);
  if (tid * 4 < PADF) {                                // zero front pads
    *(float4*)&bufA[swz4(tid*4)] = f4z;
    *(float4*)&bufB[swz4(tid*4)] = f4z;
  }
  if (chunk == 0) {                                    // true zeros at t<0
    for (int s4 = tid*4; s4 < HALO; s4 += NTH*4)
      *(float4*)&bufB[swz4(PADF + s4)] = f4z;
  }
#pragma unroll
  for (int k = 0; k < 4; ++k) {                        // coalesced state load
    int s4 = tid*4 + k*(NTH*4);
    int t  = t0 - HALO + s4;
    float4 v = f4z;
    if (t >= 0) {
      if (pass == 0) {
        float4 e = *(const float4*)&exc[rb + t];
        v = make_float4(0.5f*e.x, 0.5f*e.y, 0.5f*e.z, 0.5f*e.w);
      } else {
        v = *(const float4*)&zg[rb + t];
      }
    }
    *(float4*)&bufA[swz4(PADF + s4)] = v;
  }
  __syncthreads();

  float* cur = bufA;
  float* nxt = bufB;

  // own samples + partial sum
  float z[PT], acc[PT];
#pragma unroll
  for (int k = 0; k < PT4; ++k) {
    float4 t4 = *(const float4*)&cur[wro[k]];
    z[4*k+0] = t4.x; z[4*k+1] = t4.y; z[4*k+2] = t4.z; z[4*k+3] = t4.w;
  }
#pragma unroll
  for (int j = 0; j < PT; ++j) acc[j] = 0.f;

  // ---- evolve: 7 full steps (both passes), r0 schedule untouched ----
  for (int s = 0; s < 7; ++s) {
    const int limit = (chunk == 0) ? HALO : (s + 1) * E8;
    const bool alive = (sbase + PT > limit);
    if (alive) {
      float v[48];                         // PT + 32 floats, 16B-aligned
#pragma unroll
      for (int i = 0; i < 12; ++i) {
        float4 t4 = *(const float4*)&cur[rdo[i]];
        v[4*i+0] = t4.x; v[4*i+1] = t4.y; v[4*i+2] = t4.z; v[4*i+3] = t4.w;
      }
#pragma unroll
      for (int j = 0; j < PT; ++j) acc[j] += z[j];
#pragma unroll
      for (int j = 0; j < PT; ++j) {
        float sv = W[0] * v[j];
#pragma unroll
        for (int m = 1; m < 33; ++m) sv = fmaf(W[m], v[j+m], sv);
        z[j] = sv;
      }
      stown(nxt, wro, z);
    }
    __syncthreads();
    float* tp = cur; cur = nxt; nxt = tp;
  }

  if (pass == 0) {
    // ---- tail step 8 (s=7): no LDS store, no barrier (no reader) ----
    const int limit = (chunk == 0) ? HALO : 8 * E8;
    if (sbase + PT > limit) {
      float v[48];
#pragma unroll
      for (int i = 0; i < 12; ++i) {
        float4 t4 = *(const float4*)&cur[rdo[i]];
        v[4*i+0] = t4.x; v[4*i+1] = t4.y; v[4*i+2] = t4.z; v[4*i+3] = t4.w;
      }
#pragma unroll
      for (int j = 0; j < PT; ++j) acc[j] += z[j];
#pragma unroll
      for (int j = 0; j < PT; ++j) {
        float sv = W[0] * v[j];
#pragma unroll
        for (int m = 1; m < 33; ++m) sv = fmaf(W[m], v[j+m], sv);
        z[j] = sv;
      }
    }
    // ---- direct register->global writeback, own layout ----
    if (sbase >= HALO) {
      const size_t gb = rb + (size_t)(t0 + sbase - HALO);
#pragma unroll
      for (int k = 0; k < PT4; ++k) {
        *(float4*)&zg[gb + 4*k] = make_float4(z[4*k],   z[4*k+1],
                                              z[4*k+2], z[4*k+3]);
        *(float4*)&sg[gb + 4*k] = make_float4(acc[4*k],   acc[4*k+1],
                                              acc[4*k+2], acc[4*k+3]);
      }
    }
    return;
  }

  // ================= pass 1 epilogue (cur = y15, z = y15 own) ===========
  const int F0 = 7 * E8;
  // P0': sg in OWN layout -> register add -> one stown = E14 in nxt.
  {
#pragma unroll
    for (int k = 0; k < PT4; ++k) {
      int s4 = sbase + 4*k;
      int t  = t0 - HALO + s4;
      float4 sv = f4z;
      if (t >= 0 && (chunk == 0 || s4 >= F0 - 600))
        sv = *(const float4*)&sg[rb + t];
      acc[4*k+0] += sv.x; acc[4*k+1] += sv.y;
      acc[4*k+2] += sv.z; acc[4*k+3] += sv.w;
    }
    stown(nxt, wro, acc);                  // E14 (acc stays live = e0)
  }
  __syncthreads();

  // Rebuild taps (volatile re-reads keep the evolve loop lean); SGPR-hoist.
  Cf c;
  {
    volatile const int* vl = lenp;
    volatile const float* vp = pp;
    build_from((float)vl[0], vp[0], c);
  }
  const int L2 = 2*c.QB, L4 = 4*c.QB, LQ = c.QB, LB = c.DD + 2, LA = c.DU;
  const int L2e = (L2+3)&~3, sh2 = L2e-L2;
  const int LQe = (LQ+3)&~3, shq = LQe-LQ;
  const int LBe = (LB+3)&~3, shb = LBe-LB;
  const int LAe = (LA+3)&~3, sha = LAe-LA;
  float q4f[17], T2[12], TQ[8], TB[7], TA[5];
#pragma unroll
  for (int i = 0; i < 17; ++i) q4f[i] = sgprf(c.q4[i]);
#pragma unroll
  for (int m = 0; m < 12; ++m) {
    float v = 0.f;
#pragma unroll
    for (int i = 0; i < 9; ++i) if (m == sh2 + i) v = c.q2[i];
    T2[m] = sgprf(v);
  }
#pragma unroll
  for (int m = 0; m < 8; ++m) {
    float v = 0.f;
#pragma unroll
    for (int i = 0; i < 5; ++i) if (m == shq + i) v = c.q[i];
    TQ[m] = sgprf(v);
  }
#pragma unroll
  for (int m = 0; m < 7; ++m) {
    float v = 0.f;
#pragma unroll
    for (int i = 0; i < 4; ++i) if (m == shb + i) v = c.b[i];
    TB[m] = sgprf(v);
  }
#pragma unroll
  for (int m = 0; m < 5; ++m) {
    float v = 0.f;
#pragma unroll
    for (int i = 0; i < 2; ++i) if (m == sha + i) v = c.a[i];
    TA[m] = sgprf(v);
  }

  const bool ae = (chunk == 0) || (sbase + PT > F0);

  // Ph-A: H1 = (1+C^2)E14 ; Y2 = (1+C^2)y15 ; z62 = C^4 y15  (e0 = acc)
  float H1[PT], Y2[PT], z62[PT];
  if (ae) {
    float w[28];
    ldwin<7>(nxt, PADF + sbase - L2e, w);
#pragma unroll
    for (int j = 0; j < PT; ++j) {
      float sv = acc[j];
#pragma unroll
      for (int m = 0; m < 12; ++m) sv = fmaf(T2[m], w[j+m], sv);
      H1[j] = sv;
    }
    ldwin<7>(cur, PADF + sbase - L2e, w);
#pragma unroll
    for (int j = 0; j < PT; ++j) {
      float sv = z[j];
#pragma unroll
      for (int m = 0; m < 12; ++m) sv = fmaf(T2[m], w[j+m], sv);
      Y2[j] = sv;
    }
    float w4[32];
    ldwin<8>(cur, PADF + sbase - L4, w4);    // L4 = 4QB, multiple of 4
#pragma unroll
    for (int j = 0; j < PT; ++j) {
      float sv = q4f[0] * w4[j];
#pragma unroll
      for (int m = 1; m < 17; ++m) sv = fmaf(q4f[m], w4[j+m], sv);
      z62[j] = sv;
    }
  }
  __syncthreads();
  if (ae) { stown(nxt, wro, H1); stown(cur, wro, z62); }
  __syncthreads();

  // Ph-B: E61 = H1 + C^4 H1 + Y2
  float E61[PT];
  if (ae) {
    float w4[32];
    ldwin<8>(nxt, PADF + sbase - L4, w4);
#pragma unroll
    for (int j = 0; j < PT; ++j) {
      float sv = H1[j] + Y2[j];
#pragma unroll
      for (int m = 0; m < 17; ++m) sv = fmaf(q4f[m], w4[j+m], sv);
      E61[j] = sv;
    }
  }
  __syncthreads();
  if (ae) stown(nxt, wro, E61);
  __syncthreads();

  // Ph-C: U = E61 + C E61 + z62 ; V = C z62
  float U[PT], V[PT];
  if (ae) {
    float w[24];
    ldwin<6>(nxt, PADF + sbase - LQe, w);
#pragma unroll
    for (int j = 0; j < PT; ++j) {
      float sv = E61[j] + z62[j];
#pragma unroll
      for (int m = 0; m < 8; ++m) sv = fmaf(TQ[m], w[j+m], sv);
      U[j] = sv;
    }
    ldwin<6>(cur, PADF + sbase - LQe, w);
#pragma unroll
    for (int j = 0; j < PT; ++j) {
      float sv = TQ[0] * w[j];
#pragma unroll
      for (int m = 1; m < 8; ++m) sv = fmaf(TQ[m], w[j+m], sv);
      V[j] = sv;
    }
  }
  __syncthreads();
  if (ae) stown(nxt, wro, U);
  __syncthreads();

  // Ph-D (output threads only): s0 = U+V; ls = s0 + B U; rs = s0 + A U;
  // stored straight to global from registers (own layout).
  if (sbase >= HALO) {
    float LSv[PT], RSv[PT];
#pragma unroll
    for (int j = 0; j < PT; ++j) V[j] += U[j];
    {
      float wb[24];
      ldwin<6>(nxt, PADF + sbase - LBe, wb);
#pragma unroll
      for (int j = 0; j < PT; ++j) {
        float sv = V[j];
#pragma unroll
        for (int m = 0; m < 7; ++m) sv = fmaf(TB[m], wb[j+m], sv);
        LSv[j] = sv;
      }
    }
    {
      float wa[20];
      ldwin<5>(nxt, PADF + sbase - LAe, wa);
#pragma unroll
      for (int j = 0; j < PT; ++j) {
        float sv = V[j];
#pragma unroll
        for (int m = 0; m < 5; ++m) sv = fmaf(TA[m], wa[j+m], sv);
        RSv[j] = sv;
      }
    }
    const size_t gb = rb + (size_t)(t0 + sbase - HALO);
#pragma unroll
    for (int k = 0; k < PT4; ++k) {
      *(float4*)&lout[gb + 4*k] = make_float4(LSv[4*k],   LSv[4*k+1],
                                              LSv[4*k+2], LSv[4*k+3]);
      *(float4*)&rout[gb + 4*k] = make_float4(RSv[4*k],   RSv[4*k+1],
                                              RSv[4*k+2], RSv[4*k+3]);
    }
  }
}

extern "C" void kernel_launch(void* const* d_in, const int* in_sizes, int n_in,
                              void* d_out, int out_size, void* d_ws, size_t ws_size,
                              hipStream_t stream) {
  (void)in_sizes; (void)n_in; (void)out_size; (void)ws_size;

  const int*   lenp = (const int*)d_in[0];
  const float* pp   = (const float*)d_in[1];
  const float* exc  = (const float*)d_in[2];

  float* lout = (float*)d_out;                  // ls: 64*32000 f32
  float* rout = lout + (size_t)NROW * TLEN;     // rs

  float* zg = (float*)d_ws;                     // state y8
  float* sg = zg + (size_t)NROW * TLEN;         // partial sum y0..y7

  dim3 grid(NROW * 4);
  gs_pass<<<grid, dim3(NTH), 0, stream>>>(lenp, pp, exc, zg, sg, lout, rout, 0);
  gs_pass<<<grid, dim3(NTH), 0, stream>>>(lenp, pp, exc, zg, sg, lout, rout, 1);
}

// Round 7
// 73.577 us; speedup vs baseline: 1.6635x; 1.2112x over previous
//
#include <hip/hip_runtime.h>

// Guitar string (Karplus-Strong waveguide), MI355X gfx950.
//
// LTI reformulation (validated rounds 2-6): A (l->r, 2 taps) and B (r->l,
// 4 taps) commute; both parities evolve by C = A*B (5 taps, lag QB=DU+DD+2).
// Evolve y_m = (C^8)^m (0.5 e) (33 taps, lag 8QB); E14 = sum_{0..14} y_m;
//   E61 = (1+C^2)(1+C^4) E14 + (1+C^2) y15,  z62 = C^4 y15,
//   U = (1+C) E61 + z62,  ls = (1+B)U + C z62,  rs = (1+A)U + C z62.
//
// Round 14: rounds 8-13 each falsified a theory (reg budget, tap offload,
// C^16, flag chain, epoch trimming with extended liveness). Hard rule
// learned: the allocator pins 64 VGPRs; ANY value kept live across a
// liveness-heavy region (conv body, build_from) spills ~30+ MB and costs
// 10-25us. This round = r0 (71.8us) with exactly two liveness-NEUTRAL
// edits:
//  - P0': acc += sg in registers (own layout, validated F0-600 trim),
//    stown immediately -> acc DEAD before build_from (unlike r13, which
//    kept acc live as e0 and spilled). Removes one barrier + a full
//    16-ld/16-st LDS RMW pass. Ph-A re-reads e0 from LDS as r0 did.
//  - Ph-D: compute/stow only output threads (sbase >= HALO); sub-HALO
//    LSv/RSv was provably never read by the final coalesced store.
// Pass-0 byte-identical to r0. All other epochs untouched.
//
// Geometry: 64 rows x 4 chunks of 8000. SPAN=16384, HALO=8384 >= 8*E8
// (E8=8QB<=1048; QB<=131 since nUp+nDn=128). Pass1: F0=7*E8<=7336; epilogue
// worst-case reach 63*QB+DD+13 = 8382 <= 8384. PADF=1056 >= E8.

#define TLEN   32000
#define NROW   64
#define CHUNK  8000
#define NTH    1024
#define PT     16
#define PT4    (PT/4)
#define SPAN   (NTH*PT)        // 16384
#define HALO   (SPAN-CHUNK)    // 8384 (multiple of 16)
#define PADF   1056            // front zero pad >= E8 max (1048)
#define BUF    (PADF+SPAN)     // 17440 floats = 69.76 KB per buffer

__device__ inline int swz4(int f) {        // f: float index, multiple of 4
  int B = f >> 2;
  B ^= (B >> 3) & 7;                       // permute 16B blocks in 8-groups
  return B << 2;
}

__device__ inline float sgprf(float x) {
  return __uint_as_float(__builtin_amdgcn_readfirstlane(__float_as_uint(x)));
}

struct Cf { int DU, DD, QB; float a[2], b[4], q[5], q2[9], q4[17], q8[33]; };

__device__ inline void build_from(float Lf, float pv, Cf& c) {
  const float p   = 0.1f + 0.8f * pv;
  const float nUp = Lf * p;
  const float nDn = Lf * (1.0f - p);
  c.DU = (int)ceilf(nUp);
  c.DD = (int)ceilf(nDn);
  const float fU = (float)c.DU - nUp;
  const float fD = (float)c.DD - nDn;
  const float GN  = -0.99f * 0.999f;        // NUT * VIB
  const float GB2 = -0.99f * 0.999f * 0.5f; // BRIDGE * VIB * 0.5
  c.a[0] = GN * (1.0f - fU);                // A: lag DU - i
  c.a[1] = GN * fU;
  const float w0 = 1.0f - fD, w1 = fD;
  c.b[0] = GB2 * (0.3f * w0);               // B: lag DD+2 - i
  c.b[1] = GB2 * (w0 + 0.3f * w1);
  c.b[2] = GB2 * (0.7f * w0 + w1);
  c.b[3] = GB2 * (0.7f * w1);
  c.QB = c.DU + c.DD + 2;                   // C: lag QB - i
#pragma unroll
  for (int m = 0; m < 5; ++m) c.q[m] = 0.f;
#pragma unroll
  for (int i = 0; i < 2; ++i)
#pragma unroll
    for (int j = 0; j < 4; ++j) c.q[i+j] = fmaf(c.a[i], c.b[j], c.q[i+j]);
#pragma unroll
  for (int m = 0; m < 9; ++m) c.q2[m] = 0.f;
#pragma unroll
  for (int i = 0; i < 5; ++i)
#pragma unroll
    for (int j = 0; j < 5; ++j) c.q2[i+j] = fmaf(c.q[i], c.q[j], c.q2[i+j]);
#pragma unroll
  for (int m = 0; m < 17; ++m) c.q4[m] = 0.f;
#pragma unroll
  for (int i = 0; i < 9; ++i)
#pragma unroll
    for (int j = 0; j < 9; ++j) c.q4[i+j] = fmaf(c.q2[i], c.q2[j], c.q4[i+j]);
#pragma unroll
  for (int m = 0; m < 33; ++m) c.q8[m] = 0.f;
#pragma unroll
  for (int i = 0; i < 17; ++i)
#pragma unroll
    for (int j = 0; j < 17; ++j) c.q8[i+j] = fmaf(c.q4[i], c.q4[j], c.q8[i+j]);
}

template<int NF4>
__device__ inline void ldwin(const float* b, int basef, float* v) {
#pragma unroll
  for (int i = 0; i < NF4; ++i) {
    float4 t4 = *(const float4*)&b[swz4(basef + 4*i)];
    v[4*i+0] = t4.x; v[4*i+1] = t4.y; v[4*i+2] = t4.z; v[4*i+3] = t4.w;
  }
}

__device__ inline void stown(float* b, const int* wro, const float* v) {
#pragma unroll
  for (int k = 0; k < PT4; ++k)
    *(float4*)&b[wro[k]] = make_float4(v[4*k], v[4*k+1], v[4*k+2], v[4*k+3]);
}

__global__ __launch_bounds__(NTH, 4)
void gs_pass(const int* __restrict__ lenp, const float* __restrict__ pp,
             const float* __restrict__ exc,
             float* __restrict__ zg, float* __restrict__ sg,
             float* __restrict__ lout, float* __restrict__ rout, int pass)
{
  __shared__ __align__(16) float bufA[BUF];
  __shared__ __align__(16) float bufB[BUF];

  const int row   = blockIdx.x >> 2;
  const int chunk = blockIdx.x & 3;
  const int t0    = chunk * CHUNK;
  const int tid   = threadIdx.x;
  const int sbase = tid * PT;
  const size_t rb = (size_t)row * TLEN;
  const int steps = pass ? 7 : 8;

  // ---- taps for the evolve loop (W in SGPRs; only E8 else stays live) ----
  int E8;
  float W[33];
  {
    Cf c0; build_from((float)lenp[0], pp[0], c0);
#pragma unroll
    for (int m = 0; m < 33; ++m) W[m] = sgprf(c0.q8[m]);
    E8 = 8 * c0.QB;                       // multiple of 8, <= 1048
  }

  // ---- precomputed swizzled offsets ----
  int rdo[12], wro[PT4];
#pragma unroll
  for (int i = 0; i < 12; ++i) rdo[i] = swz4(PADF + sbase - E8 + 4*i);
#pragma unroll
  for (int k = 0; k < PT4; ++k) wro[k] = swz4(PADF + sbase + 4*k);

  // ---- staging ----
  const float4 f4z = make_float4(0.f, 0.f, 0.f, 0.f);
  if (tid * 4 < PADF) {                                // zero front pads
    *(float4*)&bufA[swz4(tid*4)] = f4z;
    *(float4*)&bufB[swz4(tid*4)] = f4z;
  }
  if (chunk == 0) {                                    // true zeros at t<0
    for (int s4 = tid*4; s4 < HALO; s4 += NTH*4)
      *(float4*)&bufB[swz4(PADF + s4)] = f4z;
  }
#pragma unroll
  for (int k = 0; k < 4; ++k) {                        // coalesced state load
    int s4 = tid*4 + k*(NTH*4);
    int t  = t0 - HALO + s4;
    float4 v = f4z;
    if (t >= 0) {
      if (pass == 0) {
        float4 e = *(const float4*)&exc[rb + t];
        v = make_float4(0.5f*e.x, 0.5f*e.y, 0.5f*e.z, 0.5f*e.w);
      } else {
        v = *(const float4*)&zg[rb + t];
      }
    }
    *(float4*)&bufA[swz4(PADF + s4)] = v;
  }
  __syncthreads();

  float* cur = bufA;
  float* nxt = bufB;

  // own samples + partial sum
  float z[PT], acc[PT];
#pragma unroll
  for (int k = 0; k < PT4; ++k) {
    float4 t4 = *(const float4*)&cur[wro[k]];
    z[4*k+0] = t4.x; z[4*k+1] = t4.y; z[4*k+2] = t4.z; z[4*k+3] = t4.w;
  }
#pragma unroll
  for (int j = 0; j < PT; ++j) acc[j] = 0.f;

  // ---- evolve (z updated in place; acc += old z first) ----
  for (int s = 0; s < steps; ++s) {
    const int limit = (chunk == 0) ? HALO : (s + 1) * E8;
    const bool alive = (sbase + PT > limit);
    if (alive) {
      float v[48];                         // PT + 32 floats, 16B-aligned
#pragma unroll
      for (int i = 0; i < 12; ++i) {
        float4 t4 = *(const float4*)&cur[rdo[i]];
        v[4*i+0] = t4.x; v[4*i+1] = t4.y; v[4*i+2] = t4.z; v[4*i+3] = t4.w;
      }
#pragma unroll
      for (int j = 0; j < PT; ++j) acc[j] += z[j];
#pragma unroll
      for (int j = 0; j < PT; ++j) {
        float sv = W[0] * v[j];
#pragma unroll
        for (int m = 1; m < 33; ++m) sv = fmaf(W[m], v[j+m], sv);
        z[j] = sv;
      }
      stown(nxt, wro, z);
    }
    __syncthreads();
    float* tp = cur; cur = nxt; nxt = tp;
  }

  if (pass == 0) {
    // cur = y8, stage acc; writeback own region.
    stown(nxt, wro, acc);
    __syncthreads();
#pragma unroll
    for (int k = 0; k < 2; ++k) {
      int s4 = HALO + tid*4 + k*(NTH*4);
      if (s4 < SPAN) {
        int t = t0 + s4 - HALO;
        *(float4*)&zg[rb + t] = *(const float4*)&cur[swz4(PADF + s4)];
        *(float4*)&sg[rb + t] = *(const float4*)&nxt[swz4(PADF + s4)];
      }
    }
    return;
  }

  // ================= pass 1 epilogue (cur = y15, z = y15 own) ===========
  const int F0 = 7 * E8;
  // P0': sg in OWN layout -> register add -> one stown = E14 in nxt;
  // acc dies HERE, before build_from (liveness-neutral vs r0 -- the r0
  // RMW held the same 4 float4 transients). One barrier, no LDS RMW pass.
  {
#pragma unroll
    for (int k = 0; k < PT4; ++k) {
      int s4 = sbase + 4*k;
      int t  = t0 - HALO + s4;
      float4 sv = f4z;
      if (t >= 0 && (chunk == 0 || s4 >= F0 - 600))
        sv = *(const float4*)&sg[rb + t];
      acc[4*k+0] += sv.x; acc[4*k+1] += sv.y;
      acc[4*k+2] += sv.z; acc[4*k+3] += sv.w;
    }
    stown(nxt, wro, acc);                  // E14; acc dead from here on
  }
  __syncthreads();

  // Rebuild taps (volatile re-reads keep the evolve loop lean); SGPR-hoist.
  Cf c;
  {
    volatile const int* vl = lenp;
    volatile const float* vp = pp;
    build_from((float)vl[0], vp[0], c);
  }
  const int L2 = 2*c.QB, L4 = 4*c.QB, LQ = c.QB, LB = c.DD + 2, LA = c.DU;
  const int L2e = (L2+3)&~3, sh2 = L2e-L2;
  const int LQe = (LQ+3)&~3, shq = LQe-LQ;
  const int LBe = (LB+3)&~3, shb = LBe-LB;
  const int LAe = (LA+3)&~3, sha = LAe-LA;
  float q4f[17], T2[12], TQ[8], TB[7], TA[5];
#pragma unroll
  for (int i = 0; i < 17; ++i) q4f[i] = sgprf(c.q4[i]);
#pragma unroll
  for (int m = 0; m < 12; ++m) {
    float v = 0.f;
#pragma unroll
    for (int i = 0; i < 9; ++i) if (m == sh2 + i) v = c.q2[i];
    T2[m] = sgprf(v);
  }
#pragma unroll
  for (int m = 0; m < 8; ++m) {
    float v = 0.f;
#pragma unroll
    for (int i = 0; i < 5; ++i) if (m == shq + i) v = c.q[i];
    TQ[m] = sgprf(v);
  }
#pragma unroll
  for (int m = 0; m < 7; ++m) {
    float v = 0.f;
#pragma unroll
    for (int i = 0; i < 4; ++i) if (m == shb + i) v = c.b[i];
    TB[m] = sgprf(v);
  }
#pragma unroll
  for (int m = 0; m < 5; ++m) {
    float v = 0.f;
#pragma unroll
    for (int i = 0; i < 2; ++i) if (m == sha + i) v = c.a[i];
    TA[m] = sgprf(v);
  }

  const bool ae = (chunk == 0) || (sbase + PT > F0);

  // Ph-A: H1 = (1+C^2)E14 ; Y2 = (1+C^2)y15 ; z62 = C^4 y15
  float H1[PT], Y2[PT], z62[PT];
  if (ae) {
    float e0[PT];
#pragma unroll
    for (int k = 0; k < PT4; ++k) {
      float4 t4 = *(const float4*)&nxt[wro[k]];
      e0[4*k+0] = t4.x; e0[4*k+1] = t4.y; e0[4*k+2] = t4.z; e0[4*k+3] = t4.w;
    }
    float w[28];
    ldwin<7>(nxt, PADF + sbase - L2e, w);
#pragma unroll
    for (int j = 0; j < PT; ++j) {
      float sv = e0[j];
#pragma unroll
      for (int m = 0; m < 12; ++m) sv = fmaf(T2[m], w[j+m], sv);
      H1[j] = sv;
    }
    ldwin<7>(cur, PADF + sbase - L2e, w);
#pragma unroll
    for (int j = 0; j < PT; ++j) {
      float sv = z[j];
#pragma unroll
      for (int m = 0; m < 12; ++m) sv = fmaf(T2[m], w[j+m], sv);
      Y2[j] = sv;
    }
    float w4[32];
    ldwin<8>(cur, PADF + sbase - L4, w4);    // L4 = 4QB, multiple of 4
#pragma unroll
    for (int j = 0; j < PT; ++j) {
      float sv = q4f[0] * w4[j];
#pragma unroll
      for (int m = 1; m < 17; ++m) sv = fmaf(q4f[m], w4[j+m], sv);
      z62[j] = sv;
    }
  }
  __syncthreads();
  if (ae) { stown(nxt, wro, H1); stown(cur, wro, z62); }
  __syncthreads();

  // Ph-B: E61 = H1 + C^4 H1 + Y2
  float E61[PT];
  if (ae) {
    float w4[32];
    ldwin<8>(nxt, PADF + sbase - L4, w4);
#pragma unroll
    for (int j = 0; j < PT; ++j) {
      float sv = H1[j] + Y2[j];
#pragma unroll
      for (int m = 0; m < 17; ++m) sv = fmaf(q4f[m], w4[j+m], sv);
      E61[j] = sv;
    }
  }
  __syncthreads();
  if (ae) stown(nxt, wro, E61);
  __syncthreads();

  // Ph-C: U = E61 + C E61 + z62 ; V = C z62
  float U[PT], V[PT];
  if (ae) {
    float w[24];
    ldwin<6>(nxt, PADF + sbase - LQe, w);
#pragma unroll
    for (int j = 0; j < PT; ++j) {
      float sv = E61[j] + z62[j];
#pragma unroll
      for (int m = 0; m < 8; ++m) sv = fmaf(TQ[m], w[j+m], sv);
      U[j] = sv;
    }
    ldwin<6>(cur, PADF + sbase - LQe, w);
#pragma unroll
    for (int j = 0; j < PT; ++j) {
      float sv = TQ[0] * w[j];
#pragma unroll
      for (int m = 1; m < 8; ++m) sv = fmaf(TQ[m], w[j+m], sv);
      V[j] = sv;
    }
  }
  __syncthreads();
  if (ae) stown(nxt, wro, U);
  __syncthreads();

  // Ph-D (output threads only -- sub-HALO results were never read):
  // s0 = U+V (into V); ls = s0 + B U; rs = s0 + A U
  const bool oe = (sbase >= HALO);
  float LSv[PT], RSv[PT];
  if (oe) {
#pragma unroll
    for (int j = 0; j < PT; ++j) V[j] += U[j];
    {
      float wb[24];
      ldwin<6>(nxt, PADF + sbase - LBe, wb);
#pragma unroll
      for (int j = 0; j < PT; ++j) {
        float sv = V[j];
#pragma unroll
        for (int m = 0; m < 7; ++m) sv = fmaf(TB[m], wb[j+m], sv);
        LSv[j] = sv;
      }
    }
    {
      float wa[20];
      ldwin<5>(nxt, PADF + sbase - LAe, wa);
#pragma unroll
      for (int j = 0; j < PT; ++j) {
        float sv = V[j];
#pragma unroll
        for (int m = 0; m < 5; ++m) sv = fmaf(TA[m], wa[j+m], sv);
        RSv[j] = sv;
      }
    }
  }
  __syncthreads();
  if (oe) { stown(cur, wro, LSv); stown(nxt, wro, RSv); }
  __syncthreads();

  // coalesced output store
#pragma unroll
  for (int k = 0; k < 2; ++k) {
    int s4 = HALO + tid*4 + k*(NTH*4);
    if (s4 < SPAN) {
      int t = t0 + s4 - HALO;
      *(float4*)&lout[rb + t] = *(const float4*)&cur[swz4(PADF + s4)];
      *(float4*)&rout[rb + t] = *(const float4*)&nxt[swz4(PADF + s4)];
    }
  }
}

extern "C" void kernel_launch(void* const* d_in, const int* in_sizes, int n_in,
                              void* d_out, int out_size, void* d_ws, size_t ws_size,
                              hipStream_t stream) {
  (void)in_sizes; (void)n_in; (void)out_size; (void)ws_size;

  const int*   lenp = (const int*)d_in[0];
  const float* pp   = (const float*)d_in[1];
  const float* exc  = (const float*)d_in[2];

  float* lout = (float*)d_out;                  // ls: 64*32000 f32
  float* rout = lout + (size_t)NROW * TLEN;     // rs

  float* zg = (float*)d_ws;                     // state y8
  float* sg = zg + (size_t)NROW * TLEN;         // partial sum y0..y7

  dim3 grid(NROW * 4);
  gs_pass<<<grid, dim3(NTH), 0, stream>>>(lenp, pp, exc, zg, sg, lout, rout, 0);
  gs_pass<<<grid, dim3(NTH), 0, stream>>>(lenp, pp, exc, zg, sg, lout, rout, 1);
}

// Round 8
// 72.237 us; speedup vs baseline: 1.6944x; 1.0186x over previous
//
#include <hip/hip_runtime.h>

// Guitar string (Karplus-Strong waveguide), MI355X gfx950.
//
// LTI reformulation (validated rounds 2-6): A (l->r, 2 taps) and B (r->l,
// 4 taps) commute; both parities evolve by C = A*B (5 taps, lag QB=DU+DD+2).
// Evolve y_m = (C^8)^m (0.5 e) (33 taps, lag 8QB); E14 = sum_{0..14} y_m;
//   E61 = (1+C^2)(1+C^4) E14 + (1+C^2) y15,  z62 = C^4 y15,
//   U = (1+C) E61 + z62,  ls = (1+B)U + C z62,  rs = (1+A)U + C z62.
//
// Round 15 = round 0 restored byte-for-byte (71.84us, best verified).
// Rounds 8-14 falsified every neighborhood direction, 6/7 by the same
// mechanism: the allocator pins this kernel at 64 VGPRs and converts ANY
// added register liveness (reg-budget pin, sgr preload, tap publish,
// C^16 window, flag-chain clobbers, P0' register adds) into per-thread
// scratch spill (WRITE_SIZE +10..100 MB, +2..50us). The r0 schedule --
// streaming 48-float window, acc/z resident, taps in SGPRs, block
// barriers as the only sync -- is a verified local optimum.
//
// Geometry: 64 rows x 4 chunks of 8000. SPAN=16384, HALO=8384 >= 8*E8
// (E8=8QB<=1048; QB<=131 since nUp+nDn=128). Pass1: F0=7*E8<=7336; epilogue
// worst-case reach 63*QB+DD+13 = 8382 <= 8384. PADF=1056 >= E8.

#define TLEN   32000
#define NROW   64
#define CHUNK  8000
#define NTH    1024
#define PT     16
#define PT4    (PT/4)
#define SPAN   (NTH*PT)        // 16384
#define HALO   (SPAN-CHUNK)    // 8384
#define PADF   1056            // front zero pad >= E8 max (1048)
#define BUF    (PADF+SPAN)     // 17440 floats = 69.76 KB per buffer

__device__ inline int swz4(int f) {        // f: float index, multiple of 4
  int B = f >> 2;
  B ^= (B >> 3) & 7;                       // permute 16B blocks in 8-groups
  return B << 2;
}

__device__ inline float sgprf(float x) {
  return __uint_as_float(__builtin_amdgcn_readfirstlane(__float_as_uint(x)));
}

struct Cf { int DU, DD, QB; float a[2], b[4], q[5], q2[9], q4[17], q8[33]; };

__device__ inline void build_from(float Lf, float pv, Cf& c) {
  const float p   = 0.1f + 0.8f * pv;
  const float nUp = Lf * p;
  const float nDn = Lf * (1.0f - p);
  c.DU = (int)ceilf(nUp);
  c.DD = (int)ceilf(nDn);
  const float fU = (float)c.DU - nUp;
  const float fD = (float)c.DD - nDn;
  const float GN  = -0.99f * 0.999f;        // NUT * VIB
  const float GB2 = -0.99f * 0.999f * 0.5f; // BRIDGE * VIB * 0.5
  c.a[0] = GN * (1.0f - fU);                // A: lag DU - i
  c.a[1] = GN * fU;
  const float w0 = 1.0f - fD, w1 = fD;
  c.b[0] = GB2 * (0.3f * w0);               // B: lag DD+2 - i
  c.b[1] = GB2 * (w0 + 0.3f * w1);
  c.b[2] = GB2 * (0.7f * w0 + w1);
  c.b[3] = GB2 * (0.7f * w1);
  c.QB = c.DU + c.DD + 2;                   // C: lag QB - i
#pragma unroll
  for (int m = 0; m < 5; ++m) c.q[m] = 0.f;
#pragma unroll
  for (int i = 0; i < 2; ++i)
#pragma unroll
    for (int j = 0; j < 4; ++j) c.q[i+j] = fmaf(c.a[i], c.b[j], c.q[i+j]);
#pragma unroll
  for (int m = 0; m < 9; ++m) c.q2[m] = 0.f;
#pragma unroll
  for (int i = 0; i < 5; ++i)
#pragma unroll
    for (int j = 0; j < 5; ++j) c.q2[i+j] = fmaf(c.q[i], c.q[j], c.q2[i+j]);
#pragma unroll
  for (int m = 0; m < 17; ++m) c.q4[m] = 0.f;
#pragma unroll
  for (int i = 0; i < 9; ++i)
#pragma unroll
    for (int j = 0; j < 9; ++j) c.q4[i+j] = fmaf(c.q2[i], c.q2[j], c.q4[i+j]);
#pragma unroll
  for (int m = 0; m < 33; ++m) c.q8[m] = 0.f;
#pragma unroll
  for (int i = 0; i < 17; ++i)
#pragma unroll
    for (int j = 0; j < 17; ++j) c.q8[i+j] = fmaf(c.q4[i], c.q4[j], c.q8[i+j]);
}

template<int NF4>
__device__ inline void ldwin(const float* b, int basef, float* v) {
#pragma unroll
  for (int i = 0; i < NF4; ++i) {
    float4 t4 = *(const float4*)&b[swz4(basef + 4*i)];
    v[4*i+0] = t4.x; v[4*i+1] = t4.y; v[4*i+2] = t4.z; v[4*i+3] = t4.w;
  }
}

__device__ inline void stown(float* b, const int* wro, const float* v) {
#pragma unroll
  for (int k = 0; k < PT4; ++k)
    *(float4*)&b[wro[k]] = make_float4(v[4*k], v[4*k+1], v[4*k+2], v[4*k+3]);
}

__global__ __launch_bounds__(NTH, 4)
void gs_pass(const int* __restrict__ lenp, const float* __restrict__ pp,
             const float* __restrict__ exc,
             float* __restrict__ zg, float* __restrict__ sg,
             float* __restrict__ lout, float* __restrict__ rout, int pass)
{
  __shared__ __align__(16) float bufA[BUF];
  __shared__ __align__(16) float bufB[BUF];

  const int row   = blockIdx.x >> 2;
  const int chunk = blockIdx.x & 3;
  const int t0    = chunk * CHUNK;
  const int tid   = threadIdx.x;
  const int sbase = tid * PT;
  const size_t rb = (size_t)row * TLEN;
  const int steps = pass ? 7 : 8;

  // ---- taps for the evolve loop (W in SGPRs; only E8 else stays live) ----
  int E8;
  float W[33];
  {
    Cf c0; build_from((float)lenp[0], pp[0], c0);
#pragma unroll
    for (int m = 0; m < 33; ++m) W[m] = sgprf(c0.q8[m]);
    E8 = 8 * c0.QB;                       // multiple of 8, <= 1048
  }

  // ---- precomputed swizzled offsets ----
  int rdo[12], wro[PT4];
#pragma unroll
  for (int i = 0; i < 12; ++i) rdo[i] = swz4(PADF + sbase - E8 + 4*i);
#pragma unroll
  for (int k = 0; k < PT4; ++k) wro[k] = swz4(PADF + sbase + 4*k);

  // ---- staging ----
  const float4 f4z = make_float4(0.f, 0.f, 0.f, 0.f);
  if (tid * 4 < PADF) {                                // zero front pads
    *(float4*)&bufA[swz4(tid*4)] = f4z;
    *(float4*)&bufB[swz4(tid*4)] = f4z;
  }
  if (chunk == 0) {                                    // true zeros at t<0
    for (int s4 = tid*4; s4 < HALO; s4 += NTH*4)
      *(float4*)&bufB[swz4(PADF + s4)] = f4z;
  }
#pragma unroll
  for (int k = 0; k < 4; ++k) {                        // coalesced state load
    int s4 = tid*4 + k*(NTH*4);
    int t  = t0 - HALO + s4;
    float4 v = f4z;
    if (t >= 0) {
      if (pass == 0) {
        float4 e = *(const float4*)&exc[rb + t];
        v = make_float4(0.5f*e.x, 0.5f*e.y, 0.5f*e.z, 0.5f*e.w);
      } else {
        v = *(const float4*)&zg[rb + t];
      }
    }
    *(float4*)&bufA[swz4(PADF + s4)] = v;
  }
  __syncthreads();

  float* cur = bufA;
  float* nxt = bufB;

  // own samples + partial sum
  float z[PT], acc[PT];
#pragma unroll
  for (int k = 0; k < PT4; ++k) {
    float4 t4 = *(const float4*)&cur[wro[k]];
    z[4*k+0] = t4.x; z[4*k+1] = t4.y; z[4*k+2] = t4.z; z[4*k+3] = t4.w;
  }
#pragma unroll
  for (int j = 0; j < PT; ++j) acc[j] = 0.f;

  // ---- evolve (z updated in place; acc += old z first) ----
  for (int s = 0; s < steps; ++s) {
    const int limit = (chunk == 0) ? HALO : (s + 1) * E8;
    const bool alive = (sbase + PT > limit);
    if (alive) {
      float v[48];                         // PT + 32 floats, 16B-aligned
#pragma unroll
      for (int i = 0; i < 12; ++i) {
        float4 t4 = *(const float4*)&cur[rdo[i]];
        v[4*i+0] = t4.x; v[4*i+1] = t4.y; v[4*i+2] = t4.z; v[4*i+3] = t4.w;
      }
#pragma unroll
      for (int j = 0; j < PT; ++j) acc[j] += z[j];
#pragma unroll
      for (int j = 0; j < PT; ++j) {
        float sv = W[0] * v[j];
#pragma unroll
        for (int m = 1; m < 33; ++m) sv = fmaf(W[m], v[j+m], sv);
        z[j] = sv;
      }
      stown(nxt, wro, z);
    }
    __syncthreads();
    float* tp = cur; cur = nxt; nxt = tp;
  }

  if (pass == 0) {
    // cur = y8, stage acc; writeback own region.
    stown(nxt, wro, acc);
    __syncthreads();
#pragma unroll
    for (int k = 0; k < 2; ++k) {
      int s4 = HALO + tid*4 + k*(NTH*4);
      if (s4 < SPAN) {
        int t = t0 + s4 - HALO;
        *(float4*)&zg[rb + t] = *(const float4*)&cur[swz4(PADF + s4)];
        *(float4*)&sg[rb + t] = *(const float4*)&nxt[swz4(PADF + s4)];
      }
    }
    return;
  }

  // ================= pass 1 epilogue (cur = y15, z = y15 own) ===========
  // P0: E14 = acc + sg (L3-hot from pass 0) into nxt.
  stown(nxt, wro, acc);
  __syncthreads();
#pragma unroll
  for (int k = 0; k < 4; ++k) {
    int s4 = tid*4 + k*(NTH*4);
    int t  = t0 - HALO + s4;
    float4 sv = f4z;
    if (t >= 0) sv = *(const float4*)&sg[rb + t];
    int o = swz4(PADF + s4);
    float4 a4 = *(const float4*)&nxt[o];
    *(float4*)&nxt[o] = make_float4(a4.x + sv.x, a4.y + sv.y,
                                    a4.z + sv.z, a4.w + sv.w);
  }
  __syncthreads();

  // Rebuild taps (volatile re-reads keep the evolve loop lean); SGPR-hoist.
  Cf c;
  {
    volatile const int* vl = lenp;
    volatile const float* vp = pp;
    build_from((float)vl[0], vp[0], c);
  }
  const int L2 = 2*c.QB, L4 = 4*c.QB, LQ = c.QB, LB = c.DD + 2, LA = c.DU;
  const int L2e = (L2+3)&~3, sh2 = L2e-L2;
  const int LQe = (LQ+3)&~3, shq = LQe-LQ;
  const int LBe = (LB+3)&~3, shb = LBe-LB;
  const int LAe = (LA+3)&~3, sha = LAe-LA;
  float q4f[17], T2[12], TQ[8], TB[7], TA[5];
#pragma unroll
  for (int i = 0; i < 17; ++i) q4f[i] = sgprf(c.q4[i]);
#pragma unroll
  for (int m = 0; m < 12; ++m) {
    float v = 0.f;
#pragma unroll
    for (int i = 0; i < 9; ++i) if (m == sh2 + i) v = c.q2[i];
    T2[m] = sgprf(v);
  }
#pragma unroll
  for (int m = 0; m < 8; ++m) {
    float v = 0.f;
#pragma unroll
    for (int i = 0; i < 5; ++i) if (m == shq + i) v = c.q[i];
    TQ[m] = sgprf(v);
  }
#pragma unroll
  for (int m = 0; m < 7; ++m) {
    float v = 0.f;
#pragma unroll
    for (int i = 0; i < 4; ++i) if (m == shb + i) v = c.b[i];
    TB[m] = sgprf(v);
  }
#pragma unroll
  for (int m = 0; m < 5; ++m) {
    float v = 0.f;
#pragma unroll
    for (int i = 0; i < 2; ++i) if (m == sha + i) v = c.a[i];
    TA[m] = sgprf(v);
  }

  const int  F0 = 7 * E8;
  const bool ae = (chunk == 0) || (sbase + PT > F0);

  // Ph-A: H1 = (1+C^2)E14 ; Y2 = (1+C^2)y15 ; z62 = C^4 y15
  float H1[PT], Y2[PT], z62[PT];
  if (ae) {
    float e0[PT];
#pragma unroll
    for (int k = 0; k < PT4; ++k) {
      float4 t4 = *(const float4*)&nxt[wro[k]];
      e0[4*k+0] = t4.x; e0[4*k+1] = t4.y; e0[4*k+2] = t4.z; e0[4*k+3] = t4.w;
    }
    float w[28];
    ldwin<7>(nxt, PADF + sbase - L2e, w);
#pragma unroll
    for (int j = 0; j < PT; ++j) {
      float sv = e0[j];
#pragma unroll
      for (int m = 0; m < 12; ++m) sv = fmaf(T2[m], w[j+m], sv);
      H1[j] = sv;
    }
    ldwin<7>(cur, PADF + sbase - L2e, w);
#pragma unroll
    for (int j = 0; j < PT; ++j) {
      float sv = z[j];
#pragma unroll
      for (int m = 0; m < 12; ++m) sv = fmaf(T2[m], w[j+m], sv);
      Y2[j] = sv;
    }
    float w4[32];
    ldwin<8>(cur, PADF + sbase - L4, w4);    // L4 = 4QB, multiple of 4
#pragma unroll
    for (int j = 0; j < PT; ++j) {
      float sv = q4f[0] * w4[j];
#pragma unroll
      for (int m = 1; m < 17; ++m) sv = fmaf(q4f[m], w4[j+m], sv);
      z62[j] = sv;
    }
  }
  __syncthreads();
  if (ae) { stown(nxt, wro, H1); stown(cur, wro, z62); }
  __syncthreads();

  // Ph-B: E61 = H1 + C^4 H1 + Y2
  float E61[PT];
  if (ae) {
    float w4[32];
    ldwin<8>(nxt, PADF + sbase - L4, w4);
#pragma unroll
    for (int j = 0; j < PT; ++j) {
      float sv = H1[j] + Y2[j];
#pragma unroll
      for (int m = 0; m < 17; ++m) sv = fmaf(q4f[m], w4[j+m], sv);
      E61[j] = sv;
    }
  }
  __syncthreads();
  if (ae) stown(nxt, wro, E61);
  __syncthreads();

  // Ph-C: U = E61 + C E61 + z62 ; V = C z62
  float U[PT], V[PT];
  if (ae) {
    float w[24];
    ldwin<6>(nxt, PADF + sbase - LQe, w);
#pragma unroll
    for (int j = 0; j < PT; ++j) {
      float sv = E61[j] + z62[j];
#pragma unroll
      for (int m = 0; m < 8; ++m) sv = fmaf(TQ[m], w[j+m], sv);
      U[j] = sv;
    }
    ldwin<6>(cur, PADF + sbase - LQe, w);
#pragma unroll
    for (int j = 0; j < PT; ++j) {
      float sv = TQ[0] * w[j];
#pragma unroll
      for (int m = 1; m < 8; ++m) sv = fmaf(TQ[m], w[j+m], sv);
      V[j] = sv;
    }
  }
  __syncthreads();
  if (ae) stown(nxt, wro, U);
  __syncthreads();

  // Ph-D: s0 = U+V (into V); ls = s0 + B U; rs = s0 + A U
  float LSv[PT], RSv[PT];
  if (ae) {
#pragma unroll
    for (int j = 0; j < PT; ++j) V[j] += U[j];
    {
      float wb[24];
      ldwin<6>(nxt, PADF + sbase - LBe, wb);
#pragma unroll
      for (int j = 0; j < PT; ++j) {
        float sv = V[j];
#pragma unroll
        for (int m = 0; m < 7; ++m) sv = fmaf(TB[m], wb[j+m], sv);
        LSv[j] = sv;
      }
    }
    {
      float wa[20];
      ldwin<5>(nxt, PADF + sbase - LAe, wa);
#pragma unroll
      for (int j = 0; j < PT; ++j) {
        float sv = V[j];
#pragma unroll
        for (int m = 0; m < 5; ++m) sv = fmaf(TA[m], wa[j+m], sv);
        RSv[j] = sv;
      }
    }
  }
  __syncthreads();
  if (ae) { stown(cur, wro, LSv); stown(nxt, wro, RSv); }
  __syncthreads();

  // coalesced output store
#pragma unroll
  for (int k = 0; k < 2; ++k) {
    int s4 = HALO + tid*4 + k*(NTH*4);
    if (s4 < SPAN) {
      int t = t0 + s4 - HALO;
      *(float4*)&lout[rb + t] = *(const float4*)&cur[swz4(PADF + s4)];
      *(float4*)&rout[rb + t] = *(const float4*)&nxt[swz4(PADF + s4)];
    }
  }
}

extern "C" void kernel_launch(void* const* d_in, const int* in_sizes, int n_in,
                              void* d_out, int out_size, void* d_ws, size_t ws_size,
                              hipStream_t stream) {
  (void)in_sizes; (void)n_in; (void)out_size; (void)ws_size;

  const int*   lenp = (const int*)d_in[0];
  const float* pp   = (const float*)d_in[1];
  const float* exc  = (const float*)d_in[2];

  float* lout = (float*)d_out;                  // ls: 64*32000 f32
  float* rout = lout + (size_t)NROW * TLEN;     // rs

  float* zg = (float*)d_ws;                     // state y8
  float* sg = zg + (size_t)NROW * TLEN;         // partial sum y0..y7

  dim3 grid(NROW * 4);
  gs_pass<<<grid, dim3(NTH), 0, stream>>>(lenp, pp, exc, zg, sg, lout, rout, 0);
  gs_pass<<<grid, dim3(NTH), 0, stream>>>(lenp, pp, exc, zg, sg, lout, rout, 1);
}